// Round 17
// baseline (878.993 us; speedup 1.0000x reference)
//
#include <hip/hip_runtime.h>
#include <math.h>

#define TB 256

typedef __attribute__((ext_vector_type(8))) short bf16x8;
typedef __attribute__((ext_vector_type(4))) float f32x4;

__device__ __forceinline__ float fast_sigmoid(float x) {
    return 1.0f / (1.0f + __expf(-x));
}
__device__ __forceinline__ float fast_tanh(float x) {
    float a = fabsf(x);
    float e = __expf(2.0f * a);
    float r = 1.0f - 2.0f / (e + 1.0f);
    return copysignf(r, x);
}
// tanh-form GELU: max |err| vs exact ~3e-4, far below the 2e-2 threshold
__device__ __forceinline__ float fast_gelu(float x) {
    float x3 = x * x * x;
    return 0.5f * x * (1.0f + fast_tanh(0.7978845608028654f * (x + 0.044715f * x3)));
}
// fp32 -> bf16 (RNE)
__device__ __forceinline__ short f2bf(float f) {
    unsigned u = __float_as_uint(f);
    unsigned r = (u + 0x7FFFu + ((u >> 16) & 1u)) >> 16;
    return (short)r;
}

// ---------------------------------------------------------------------------
// LDS pool (floats), 56.4 KB. kq/vWT and slots double-buffered; whh stored
// with 8-chunk XOR swizzle (chunk ^= (e>>3)&7) so the 3-row reads by thread
// (s,d) (rows d, d+32, d+64) are bank-conflict-free.
// ---------------------------------------------------------------------------
#define P_A12   0        // 4096 : A12 [c][col] stride 128   (setup: staged wih)
#define P_C12   4096     // 128
#define P_WHH   4224     // 3456 : whh [e][chunk-swz] stride 36 (setup: v/k/q, MvW)
#define P_VWT0  7680     // 1920 : vWT buf0 [e][n-swz] stride 20 (setup: staged wts)
#define P_VWT1  9600     // 1920 : vWT buf1
#define P_KQ0   11520    // 576  : kq buf0 [n][d] stride 36  (setup: Mkq 1024)
#define P_KQ1   12096    // 576  : kq buf1
#define P_X     12672    // 576  : X [n][k] stride 36
#define P_FEAT  13248    // 576  : feat [n][c] stride 36     (setup: MvW tail)
#define P_SL0   13824    // 144  : slots buf0 [s][d] stride 36
#define P_SL1   13968    // 144  : slots buf1
#define P_SZ    14112

// ---------------------------------------------------------------------------
// Kernel A: single-phase iterations (3 barriers/step, was 7).
// Per iteration phase:
//   tid<128 (thread (s=tid>>5, d=tid&31)):
//     redundant logits (lane=(s',n') one dot) + shfl-softmax -> attn in regs;
//     ar[16] via shfl; gh (3 dots, swizzled whh LDS); gi (3 dots, vWT);
//     GRU combine -> slots buf^1 (+traj at it2).
//   tid>=128: it0 conv(t+1)->feat; it1/it2 P2(t+1) halves -> kq/vWT buf^1;
//     it2 also X(t+2) prefetch (issue-early/write-late).
// Prologue: conv(0) (tid>=128) | P2(0) all threads + X(1).
// Fused weights (verified rounds 2-16):
//   Mkq[d][dp] = sum_e k_w[e][d] q_w[e][dp]
//   MvW[d][e]  = sum_e' v_w[e'][d] wih[e][e']
//   A12[c][col] = sum_d wts[d][c] * (col<32 ? Mkq[d][col] : MvW[d][col-32])
//   c12[col]    = sum_d bts[d]   * (same)
// ---------------------------------------------------------------------------
__global__ __launch_bounds__(256, 2) void slot_recur_kernel(
    const float* __restrict__ frames, const float* __restrict__ slot_mu,
    const float* __restrict__ conv_w, const float* __restrict__ conv_b,
    const float* __restrict__ to_slot_w, const float* __restrict__ to_slot_b,
    const float* __restrict__ q_w, const float* __restrict__ k_w,
    const float* __restrict__ v_w,
    const float* __restrict__ wih, const float* __restrict__ whh,
    const float* __restrict__ bih, const float* __restrict__ bhh,
    float* __restrict__ slots_out)
{
    const int tid = threadIdx.x;
    const int b = blockIdx.x;
    const int lane = tid & 63;

    __shared__ float pool[P_SZ];

    // ---- S0: stage raw weights ----
    for (int i = tid; i < 3072; i += 256) pool[P_A12 + i] = wih[i];
    for (int i = tid; i < 1024; i += 256) {
        pool[P_WHH + i]        = v_w[i];
        pool[P_WHH + 1024 + i] = k_w[i];
        pool[P_WHH + 2048 + i] = q_w[i];
        pool[P_VWT0 + i]       = to_slot_w[i];
    }
    __syncthreads();

    // ---- S1a: Mkq -> P_KQ0 scratch ----
    for (int o = tid; o < 1024; o += 256) {
        int d = o >> 5, dp = o & 31;
        float acc = 0.f;
#pragma unroll 8
        for (int e = 0; e < 32; ++e)
            acc += pool[P_WHH + 1024 + e * 32 + d] * pool[P_WHH + 2048 + e * 32 + dp];
        pool[P_KQ0 + o] = acc;
    }
    __syncthreads();

    // ---- S1b: MvW split (P_WHH+1024 head, P_FEAT tail) ----
    for (int o = tid; o < 3072; o += 256) {
        int d = o / 96, e = o - d * 96;
        float acc = 0.f;
#pragma unroll 8
        for (int ep = 0; ep < 32; ++ep)
            acc += pool[P_WHH + ep * 32 + d] * pool[P_A12 + e * 32 + ep];
        if (o < 2432) pool[P_WHH + 1024 + o] = acc;
        else          pool[P_FEAT + o - 2432] = acc;
    }
    __syncthreads();

    // ---- S2: A12/c12 ----
    for (int o = tid; o < 4096; o += 256) {
        int c = o >> 7, col = o & 127;
        float acc = 0.f;
        if (col < 32) {
#pragma unroll 8
            for (int d = 0; d < 32; ++d)
                acc += pool[P_VWT0 + d * 32 + c] * pool[P_KQ0 + d * 32 + col];
        } else {
            int e = col - 32;
#pragma unroll 8
            for (int d = 0; d < 32; ++d) {
                int i = d * 96 + e;
                float mv = (i < 2432) ? pool[P_WHH + 1024 + i] : pool[P_FEAT + i - 2432];
                acc += pool[P_VWT0 + d * 32 + c] * mv;
            }
        }
        pool[P_A12 + c * 128 + col] = acc;
    }
    if (tid < 128) {
        int col = tid;
        float acc = 0.f;
        if (col < 32) {
            for (int d = 0; d < 32; ++d)
                acc += to_slot_b[d] * pool[P_KQ0 + d * 32 + col];
        } else {
            int e = col - 32;
            for (int d = 0; d < 32; ++d) {
                int i = d * 96 + e;
                float mv = (i < 2432) ? pool[P_WHH + 1024 + i] : pool[P_FEAT + i - 2432];
                acc += to_slot_b[d] * mv;
            }
        }
        pool[P_C12 + col] = acc;
    }
    __syncthreads();

    // ---- S3: swizzled whh -> LDS; biases/regs; slots init; X(0) ----
    for (int i = tid; i < 3072; i += 256) {
        int e = i >> 5, el = i & 31;
        int c = el >> 2, wq = el & 3;
        pool[P_WHH + e * 36 + (((c ^ ((e >> 3) & 7)) << 2) | wq)] = whh[i];
    }
    const int dB = tid & 31;
    const int sB = tid >> 5;          // valid for tid<128
    const int tid2 = tid - 128;       // valid for tid>=128
    const int o_c = tid & 31;
    float bi0 = 0.f, bi1 = 0.f, bi2 = 0.f;
    float bh0 = 0.f, bh1 = 0.f, bh2 = 0.f;
    if (tid < 128) {
        bi0 = bih[dB]; bi1 = bih[32 + dB]; bi2 = bih[64 + dB];
        bh0 = bhh[dB]; bh1 = bhh[32 + dB]; bh2 = bhh[64 + dB];
        pool[P_SL0 + sB * 36 + dB] = slot_mu[tid];
    }
    float4 cw4[8];
    float cb = 0.f;
    if (tid >= 128) {
        const float4* wp = (const float4*)(conv_w + o_c * 32);
#pragma unroll
        for (int c = 0; c < 8; ++c) cw4[c] = wp[c];
        cb = conv_b[o_c];
    }

    const float* fb = frames + (size_t)b * (128 * 256);
    if (tid < 128) {
        int h = tid >> 6, ll = tid & 63;
        int i = ll >> 2, j4 = ll & 3;
        float4 v = *(const float4*)&fb[(h ? 0 : 256) + i * 16 + j4 * 4];
        int n = (i >> 2) * 4 + j4, p = i & 3;
        *(float4*)&pool[P_X + n * 36 + h * 16 + p * 4] = v;
    }
    __syncthreads();

    // ---- Prologue: conv(0) on tid>=128 (4 rows/thread) ----
    if (tid >= 128) {
        int rg = tid2 >> 5;
#pragma unroll
        for (int j = 0; j < 4; ++j) {
            int n = rg * 4 + j;
            const float* xr = &pool[P_X + n * 36];
            float acc = cb;
#pragma unroll
            for (int c = 0; c < 8; ++c) {
                float4 x4 = *(const float4*)&xr[c * 4];
                acc += cw4[c].x * x4.x + cw4[c].y * x4.y + cw4[c].z * x4.z + cw4[c].w * x4.w;
            }
            pool[P_FEAT + n * 36 + o_c] = fast_gelu(acc);
        }
    }
    __syncthreads();

    // ---- Prologue: P2(0) all threads -> buf0; X(1) prefetch tid<128 ----
    {
        float4 pf;
        const bool havepf = (tid < 128);
        if (havepf) {
            int h = tid >> 6, ll = tid & 63;
            int i = ll >> 2, j4 = ll & 3;
            pf = *(const float4*)&fb[(0 + (h ? 1 : 2)) * 256 + i * 16 + j4 * 4];
        }
        const int cg = tid & 63;
        const int wv = tid >> 6;
        const int col0 = cg * 2;
        float accx[4], accy[4];
#pragma unroll
        for (int j = 0; j < 4; ++j) { accx[j] = 0.f; accy[j] = 0.f; }
#pragma unroll
        for (int c = 0; c < 32; c += 4) {
            float2 a0 = *(const float2*)&pool[P_A12 + (c + 0) * 128 + col0];
            float2 a1 = *(const float2*)&pool[P_A12 + (c + 1) * 128 + col0];
            float2 a2 = *(const float2*)&pool[P_A12 + (c + 2) * 128 + col0];
            float2 a3 = *(const float2*)&pool[P_A12 + (c + 3) * 128 + col0];
#pragma unroll
            for (int j = 0; j < 4; ++j) {
                float4 q = *(const float4*)&pool[P_FEAT + (wv * 4 + j) * 36 + c];
                accx[j] += a0.x * q.x + a1.x * q.y + a2.x * q.z + a3.x * q.w;
                accy[j] += a0.y * q.x + a1.y * q.y + a2.y * q.z + a3.y * q.w;
            }
        }
        float cx = pool[P_C12 + col0], cy = pool[P_C12 + col0 + 1];
        if (col0 < 32) {
#pragma unroll
            for (int j = 0; j < 4; ++j) {
                int n = wv * 4 + j;
                *(float2*)&pool[P_KQ0 + n * 36 + col0] =
                    make_float2(accx[j] + cx, accy[j] + cy);
            }
        } else {
            int e0 = col0 - 32;
            int sw0 = (e0 >> 3) & 3;
            int sw1 = ((e0 + 1) >> 3) & 3;
            float* r0 = &pool[P_VWT0 + e0 * 20 + ((wv ^ sw0) << 2)];
            float* r1 = &pool[P_VWT0 + (e0 + 1) * 20 + ((wv ^ sw1) << 2)];
#pragma unroll
            for (int j = 0; j < 4; ++j) {
                r0[j] = accx[j] + cx;
                r1[j] = accy[j] + cy;
            }
        }
        if (havepf) {
            int h = tid >> 6, ll = tid & 63;
            int i = ll >> 2, j4 = ll & 3;
            int n = (i >> 2) * 4 + j4, p = i & 3;
            *(float4*)&pool[P_X + n * 36 + h * 16 + p * 4] = pf;
        }
    }
    __syncthreads();

    float* so = slots_out + (size_t)b * (126 * 128);
    int scur = 0, kcur = 0;

#pragma unroll 1
    for (int t = 0; t < 126; ++t) {
        const int kc = kcur, kn = kcur ^ 1;
#pragma unroll 1
        for (int it = 0; it < 3; ++it) {
            if (tid < 128) {
                const float* slc = &pool[P_SL0 + scur * 144];
                const float* kqc = &pool[P_KQ0 + kc * 576];
                const float* vwc = &pool[P_VWT0 + kc * 1920];

                // redundant logits: lane = (s', n')
                int sp_ = lane >> 4, np_ = lane & 15;
                const float* sp = &slc[sp_ * 36];
                const float* kp = &kqc[np_ * 36];
                float lg = 0.f;
#pragma unroll
                for (int d = 0; d < 32; d += 4) {
                    float4 a = *(const float4*)&sp[d];
                    float4 c = *(const float4*)&kp[d];
                    lg += a.x * c.x + a.y * c.y + a.z * c.z + a.w * c.w;
                }
                lg *= 0.17677669529663687f;   // 1/sqrt(32)
                float m = fmaxf(lg, __shfl_xor(lg, 16));
                m = fmaxf(m, __shfl_xor(m, 32));
                float e = __expf(lg - m);
                float ss = e + __shfl_xor(e, 16);
                ss += __shfl_xor(ss, 32);
                float av = e / ss;
                float ar[16];
#pragma unroll
                for (int n = 0; n < 16; ++n) ar[n] = __shfl(av, (sB & 3) * 16 + n);

                // gh: 3 dots of 32 (swizzled whh), slots row chunk-wise
                const int s3a = (dB >> 3) & 7;
                const int s3b = s3a ^ 4;
                const float* wr0 = &pool[P_WHH + dB * 36];
                const float* wr1 = &pool[P_WHH + (dB + 32) * 36];
                const float* wr2 = &pool[P_WHH + (dB + 64) * 36];
                const float* srp = &slc[sB * 36];
                float hval = srp[dB];
                float gh0 = bh0, gh1 = bh1, gh2 = bh2;
#pragma unroll
                for (int c = 0; c < 8; ++c) {
                    float4 s4 = *(const float4*)&srp[c * 4];
                    float4 w0 = *(const float4*)&wr0[(c ^ s3a) << 2];
                    float4 w1 = *(const float4*)&wr1[(c ^ s3b) << 2];
                    float4 w2 = *(const float4*)&wr2[(c ^ s3a) << 2];
                    gh0 += s4.x * w0.x + s4.y * w0.y + s4.z * w0.z + s4.w * w0.w;
                    gh1 += s4.x * w1.x + s4.y * w1.y + s4.z * w1.z + s4.w * w1.w;
                    gh2 += s4.x * w2.x + s4.y * w2.y + s4.z * w2.z + s4.w * w2.w;
                }

                // gi: 3 dots of 16 (swizzled vWT)
                const int sw = (dB >> 3) & 3;
                const float* v0 = &vwc[dB * 20];
                const float* v1 = &vwc[(dB + 32) * 20];
                const float* v2 = &vwc[(dB + 64) * 20];
                float gir = bi0, giz = bi1, gin = bi2;
#pragma unroll
                for (int n4 = 0; n4 < 4; ++n4) {
                    int ph = (n4 ^ sw) << 2;
                    float4 x0 = *(const float4*)&v0[ph];
                    float4 x1 = *(const float4*)&v1[ph];
                    float4 x2 = *(const float4*)&v2[ph];
                    int n = n4 * 4;
                    gir += ar[n] * x0.x + ar[n + 1] * x0.y + ar[n + 2] * x0.z + ar[n + 3] * x0.w;
                    giz += ar[n] * x1.x + ar[n + 1] * x1.y + ar[n + 2] * x1.z + ar[n + 3] * x1.w;
                    gin += ar[n] * x2.x + ar[n + 1] * x2.y + ar[n + 2] * x2.z + ar[n + 3] * x2.w;
                }
                float r = fast_sigmoid(gir + gh0);
                float z = fast_sigmoid(giz + gh1);
                float nn = fast_tanh(gin + r * gh2);
                float hn = (1.0f - z) * nn + z * hval;
                pool[P_SL0 + (scur ^ 1) * 144 + sB * 36 + dB] = hn;
                if (it == 2) so[t * 128 + tid] = hn;
            } else {
                if (it == 0) {
                    if (t < 125) {
                        int rg = tid2 >> 5;
#pragma unroll
                        for (int j = 0; j < 4; ++j) {
                            int n = rg * 4 + j;
                            const float* xr = &pool[P_X + n * 36];
                            float acc = cb;
#pragma unroll
                            for (int c = 0; c < 8; ++c) {
                                float4 x4 = *(const float4*)&xr[c * 4];
                                acc += cw4[c].x * x4.x + cw4[c].y * x4.y
                                     + cw4[c].z * x4.z + cw4[c].w * x4.w;
                            }
                            pool[P_FEAT + n * 36 + o_c] = fast_gelu(acc);
                        }
                    }
                } else {
                    float4 pfx;
                    const bool ldx = (it == 2) && (t < 124);
                    if (ldx) {
                        int h = tid2 >> 6, ll = tid2 & 63;
                        int i = ll >> 2, j4 = ll & 3;
                        pfx = *(const float4*)&fb[(t + (h ? 2 : 3)) * 256 + i * 16 + j4 * 4];
                    }
                    if (t < 125) {
                        // P2(t+1) half: 2 cols x 4 rows
                        const int cg2 = tid2 & 63;
                        const int rh = tid2 >> 6;
                        const int col0 = cg2 * 2;
                        const int r0w = rh * 8 + (it - 1) * 4;
                        float accx[4], accy[4];
#pragma unroll
                        for (int j = 0; j < 4; ++j) { accx[j] = 0.f; accy[j] = 0.f; }
#pragma unroll
                        for (int c = 0; c < 32; c += 4) {
                            float2 a0 = *(const float2*)&pool[P_A12 + (c + 0) * 128 + col0];
                            float2 a1 = *(const float2*)&pool[P_A12 + (c + 1) * 128 + col0];
                            float2 a2 = *(const float2*)&pool[P_A12 + (c + 2) * 128 + col0];
                            float2 a3 = *(const float2*)&pool[P_A12 + (c + 3) * 128 + col0];
#pragma unroll
                            for (int j = 0; j < 4; ++j) {
                                float4 q = *(const float4*)&pool[P_FEAT + (r0w + j) * 36 + c];
                                accx[j] += a0.x * q.x + a1.x * q.y + a2.x * q.z + a3.x * q.w;
                                accy[j] += a0.y * q.x + a1.y * q.y + a2.y * q.z + a3.y * q.w;
                            }
                        }
                        float cx = pool[P_C12 + col0], cy = pool[P_C12 + col0 + 1];
                        if (col0 < 32) {
#pragma unroll
                            for (int j = 0; j < 4; ++j) {
                                int n = r0w + j;
                                *(float2*)&pool[P_KQ0 + kn * 576 + n * 36 + col0] =
                                    make_float2(accx[j] + cx, accy[j] + cy);
                            }
                        } else {
                            int e0 = col0 - 32;
                            int sw0 = (e0 >> 3) & 3;
                            int sw1 = ((e0 + 1) >> 3) & 3;
                            int lc = rh * 2 + (it - 1);   // logical chunk
                            float* fr0 = &pool[P_VWT0 + kn * 1920 + e0 * 20 + ((lc ^ sw0) << 2)];
                            float* fr1 = &pool[P_VWT0 + kn * 1920 + (e0 + 1) * 20 + ((lc ^ sw1) << 2)];
#pragma unroll
                            for (int j = 0; j < 4; ++j) {
                                fr0[j] = accx[j] + cx;
                                fr1[j] = accy[j] + cy;
                            }
                        }
                    }
                    if (ldx) {
                        int h = tid2 >> 6, ll = tid2 & 63;
                        int i = ll >> 2, j4 = ll & 3;
                        int n = (i >> 2) * 4 + j4, p = i & 3;
                        *(float4*)&pool[P_X + n * 36 + h * 16 + p * 4] = pfx;
                    }
                }
            }
            __syncthreads();
            scur ^= 1;
        }
        kcur ^= 1;
    }
}

// ---------------------------------------------------------------------------
// Kernel B (decode_mfma): byte-identical to round-15/16 verified version.
// ---------------------------------------------------------------------------
__global__ __launch_bounds__(TB, 1) void decode_mfma(
    const float* __restrict__ slots_traj, const float* __restrict__ frames,
    const float* __restrict__ dec_w, const float* __restrict__ dec_b,
    const float* __restrict__ deconv_w, const float* __restrict__ deconv_b,
    float* __restrict__ out)
{
    const int tid = threadIdx.x;
    const int l = tid & 63;
    const int w = tid >> 6;
    const int m0 = blockIdx.x * 64;

    __shared__ short A_lds[64 * 136];
    __shared__ short B_lds[64 * 136];
    __shared__ float dw_s[512];
    __shared__ float dbd_s[256];

    {
        int row = tid >> 2, kq = (tid & 3) * 32;
        const float* src = slots_traj + (size_t)(m0 + row) * 128 + kq;
        short tmp[32];
#pragma unroll
        for (int i = 0; i < 32; i += 4) {
            float4 v = *(const float4*)&src[i];
            tmp[i] = f2bf(v.x); tmp[i + 1] = f2bf(v.y);
            tmp[i + 2] = f2bf(v.z); tmp[i + 3] = f2bf(v.w);
        }
        short* dst = &A_lds[row * 136 + kq];
#pragma unroll
        for (int i = 0; i < 4; ++i)
            *(bf16x8*)&dst[i * 8] = *(bf16x8*)&tmp[i * 8];
    }
    for (int i = tid; i < 512; i += TB) dw_s[i] = deconv_w[i];
    {
        int sp = tid >> 4, kl = tid & 15;
        float acc = 0.f;
#pragma unroll 8
        for (int c = 0; c < 32; ++c)
            acc += dec_b[16 * c + sp] * deconv_w[c * 16 + kl];
        dbd_s[tid] = acc;
    }
    __syncthreads();

    bf16x8 afr[4];
#pragma unroll
    for (int ks = 0; ks < 4; ++ks)
        afr[ks] = *(const bf16x8*)&A_lds[(16 * w + (l & 15)) * 136 + ks * 32 + (l >> 4) * 8];

    float part[4][16];
#pragma unroll
    for (int r = 0; r < 4; ++r)
#pragma unroll
        for (int kl = 0; kl < 16; ++kl) part[r][kl] = 0.f;

#pragma unroll 1
    for (int ch = 0; ch < 8; ++ch) {
        {
            int row = tid >> 2, kq = (tid & 3) * 32;
            const float* src = dec_w + (size_t)(ch * 64 + row) * 128 + kq;
            short tmp[32];
#pragma unroll
            for (int i = 0; i < 32; i += 4) {
                float4 v = *(const float4*)&src[i];
                tmp[i] = f2bf(v.x); tmp[i + 1] = f2bf(v.y);
                tmp[i + 2] = f2bf(v.z); tmp[i + 3] = f2bf(v.w);
            }
            short* dst = &B_lds[row * 136 + kq];
#pragma unroll
            for (int i = 0; i < 4; ++i)
                *(bf16x8*)&dst[i * 8] = *(bf16x8*)&tmp[i * 8];
        }
        __syncthreads();

#pragma unroll
        for (int ct = 0; ct < 4; ++ct) {
            f32x4 acc = {0.f, 0.f, 0.f, 0.f};
#pragma unroll
            for (int ks = 0; ks < 4; ++ks) {
                bf16x8 bfr = *(const bf16x8*)&B_lds[(ct * 16 + (l & 15)) * 136 + ks * 32 + (l >> 4) * 8];
                acc = __builtin_amdgcn_mfma_f32_16x16x32_bf16(afr[ks], bfr, acc, 0, 0, 0);
            }
            const float* dwp = &dw_s[(4 * ch + ct) * 16];
#pragma unroll
            for (int r = 0; r < 4; ++r) {
                float v = acc[r];
#pragma unroll
                for (int kl = 0; kl < 16; ++kl) part[r][kl] += v * dwp[kl];
            }
        }
        __syncthreads();
    }

    const int sp = l & 15;
    const int bi = sp >> 2, bj = sp & 3;
    const float db0 = deconv_b[0];
    float dbdv[16];
#pragma unroll
    for (int kl = 0; kl < 16; ++kl) dbdv[kl] = dbd_s[sp * 16 + kl];

#pragma unroll
    for (int r = 0; r < 4; ++r) {
        int mrow = m0 + 16 * w + (l >> 4) * 4 + r;
        int bb = mrow / 126, tt = mrow - bb * 126;
        const float* fr = frames + ((size_t)bb * 128 + (tt + 1)) * 256;
        float* op = out + (size_t)mrow * 256;
#pragma unroll
        for (int kk = 0; kk < 4; ++kk) {
            int pixb = (bi * 4 + kk) * 16 + bj * 4;
            float4 c4 = *(const float4*)&fr[pixb];
            float4 o4;
            o4.x = fminf(fmaxf(c4.x + tanhf(part[r][kk * 4 + 0] + dbdv[kk * 4 + 0] + db0), 0.f), 1.f);
            o4.y = fminf(fmaxf(c4.y + tanhf(part[r][kk * 4 + 1] + dbdv[kk * 4 + 1] + db0), 0.f), 1.f);
            o4.z = fminf(fmaxf(c4.z + tanhf(part[r][kk * 4 + 2] + dbdv[kk * 4 + 2] + db0), 0.f), 1.f);
            o4.w = fminf(fmaxf(c4.w + tanhf(part[r][kk * 4 + 3] + dbdv[kk * 4 + 3] + db0), 0.f), 1.f);
            *(float4*)&op[pixb] = o4;
        }
    }
}

extern "C" void kernel_launch(void* const* d_in, const int* in_sizes, int n_in,
                              void* d_out, int out_size, void* d_ws, size_t ws_size,
                              hipStream_t stream) {
    const float* frames    = (const float*)d_in[0];
    const float* slot_mu   = (const float*)d_in[1];
    const float* conv_w    = (const float*)d_in[2];
    const float* conv_b    = (const float*)d_in[3];
    const float* to_slot_w = (const float*)d_in[4];
    const float* to_slot_b = (const float*)d_in[5];
    const float* q_w       = (const float*)d_in[6];
    const float* k_w       = (const float*)d_in[7];
    const float* v_w       = (const float*)d_in[8];
    const float* gru_wih   = (const float*)d_in[9];
    const float* gru_whh   = (const float*)d_in[10];
    const float* gru_bih   = (const float*)d_in[11];
    const float* gru_bhh   = (const float*)d_in[12];
    const float* dec_w     = (const float*)d_in[13];
    const float* dec_b     = (const float*)d_in[14];
    const float* deconv_w  = (const float*)d_in[15];
    const float* deconv_b  = (const float*)d_in[16];

    float* slots_traj = (float*)d_ws;  // 512*126*128 floats = 33 MB
    float* outp = (float*)d_out;

    hipLaunchKernelGGL(slot_recur_kernel, dim3(512), dim3(256), 0, stream,
                       frames, slot_mu, conv_w, conv_b, to_slot_w, to_slot_b,
                       q_w, k_w, v_w, gru_wih, gru_whh, gru_bih, gru_bhh,
                       slots_traj);
    hipLaunchKernelGGL(decode_mfma, dim3(64512 / 64), dim3(TB), 0, stream,
                       slots_traj, frames, dec_w, dec_b, deconv_w, deconv_b,
                       outp);
}

// Round 18
// 688.290 us; speedup vs baseline: 1.2771x; 1.2771x over previous
//
#include <hip/hip_runtime.h>
#include <math.h>

#define TB 256

typedef __attribute__((ext_vector_type(8))) short bf16x8;
typedef __attribute__((ext_vector_type(4))) float f32x4;

__device__ __forceinline__ float fast_sigmoid(float x) {
    return 1.0f / (1.0f + __expf(-x));
}
__device__ __forceinline__ float fast_tanh(float x) {
    float a = fabsf(x);
    float e = __expf(2.0f * a);
    float r = 1.0f - 2.0f / (e + 1.0f);
    return copysignf(r, x);
}
// tanh-form GELU: max |err| vs exact ~3e-4, far below the 2e-2 threshold
__device__ __forceinline__ float fast_gelu(float x) {
    float x3 = x * x * x;
    return 0.5f * x * (1.0f + fast_tanh(0.7978845608028654f * (x + 0.044715f * x3)));
}
// fp32 -> bf16 (RNE)
__device__ __forceinline__ short f2bf(float f) {
    unsigned u = __float_as_uint(f);
    unsigned r = (u + 0x7FFFu + ((u >> 16) & 1u)) >> 16;
    return (short)r;
}

// ---------------------------------------------------------------------------
// LDS pool (floats), 48.6 KB (round-14/16 layout, verified).
// ---------------------------------------------------------------------------
#define P_A12   0        // 4096 : A12 [c][col] stride 128
#define P_C12   4096     // 128
#define P_WHH   4224     // 3456 : setup scratch (staged v/k/q, MvW split)
#define P_VWT   7680     // 1920 : vWT [e][n-swizzled] stride 20
#define P_KQ    9600     // 576  : kq  [n][d] stride 36
#define P_X     10176    // 576  : X   [n][k] stride 36
#define P_FEAT  10752    // 576  : feat[n][c] stride 36
#define P_SLOTS 11328    // 144  : slots [s][d] stride 36
#define P_ATTN  11472    // 80   : attn [s][n] stride 20
#define P_GH    11552    // 400  : gh [s][e] stride 100
#define P_SZ    12144

// ---------------------------------------------------------------------------
// Kernel A: round-16 verified structure (709 us) + (a) float4 vWT stores in
// P2 (was 8 scalar b32 at 4-way-conflicted stride), (b) setprio around the
// phase-B critical chain (role-split vs conv on tid>=128).
// Per step: P2 KQV + X(t+1) prefetch | 3x { [wave0 logits+softmax || waves1-3
// gh] | [tid<128 gi+combine || tid>=128 conv(t+1) halves] }. 7 barriers/step.
// Fused weights (verified rounds 2-16):
//   Mkq[d][dp] = sum_e k_w[e][d] q_w[e][dp]
//   MvW[d][e]  = sum_e' v_w[e'][d] wih[e][e']
//   A12[c][col] = sum_d wts[d][c] * (col<32 ? Mkq[d][col] : MvW[d][col-32])
//   c12[col]    = sum_d bts[d]   * (same)
// ---------------------------------------------------------------------------
__global__ __launch_bounds__(256, 2) void slot_recur_kernel(
    const float* __restrict__ frames, const float* __restrict__ slot_mu,
    const float* __restrict__ conv_w, const float* __restrict__ conv_b,
    const float* __restrict__ to_slot_w, const float* __restrict__ to_slot_b,
    const float* __restrict__ q_w, const float* __restrict__ k_w,
    const float* __restrict__ v_w,
    const float* __restrict__ wih, const float* __restrict__ whh,
    const float* __restrict__ bih, const float* __restrict__ bhh,
    float* __restrict__ slots_out)
{
    const int tid = threadIdx.x;
    const int b = blockIdx.x;
    const int lane = tid & 63;
    const int wid = tid >> 6;

    __shared__ float pool[P_SZ];

    // ---- S0: stage raw weights into aliased regions ----
    for (int i = tid; i < 3072; i += 256) pool[P_A12 + i] = wih[i];
    for (int i = tid; i < 1024; i += 256) {
        pool[P_WHH + i]        = v_w[i];
        pool[P_WHH + 1024 + i] = k_w[i];
        pool[P_WHH + 2048 + i] = q_w[i];
        pool[P_VWT + i]        = to_slot_w[i];
    }
    __syncthreads();

    // ---- S1a: Mkq ----
    for (int o = tid; o < 1024; o += 256) {
        int d = o >> 5, dp = o & 31;
        float acc = 0.f;
#pragma unroll 8
        for (int e = 0; e < 32; ++e)
            acc += pool[P_WHH + 1024 + e * 32 + d] * pool[P_WHH + 2048 + e * 32 + dp];
        pool[P_KQ + o] = acc;
    }
    __syncthreads();

    // ---- S1b: MvW (split store) ----
    for (int o = tid; o < 3072; o += 256) {
        int d = o / 96, e = o - d * 96;
        float acc = 0.f;
#pragma unroll 8
        for (int ep = 0; ep < 32; ++ep)
            acc += pool[P_WHH + ep * 32 + d] * pool[P_A12 + e * 32 + ep];
        if (o < 2432) pool[P_WHH + 1024 + o] = acc;
        else          pool[P_FEAT + o - 2432] = acc;
    }
    __syncthreads();

    // ---- S2: A12/c12 ----
    for (int o = tid; o < 4096; o += 256) {
        int c = o >> 7, col = o & 127;
        float acc = 0.f;
        if (col < 32) {
#pragma unroll 8
            for (int d = 0; d < 32; ++d)
                acc += pool[P_VWT + d * 32 + c] * pool[P_KQ + d * 32 + col];
        } else {
            int e = col - 32;
#pragma unroll 8
            for (int d = 0; d < 32; ++d) {
                int i = d * 96 + e;
                float mv = (i < 2432) ? pool[P_WHH + 1024 + i] : pool[P_FEAT + i - 2432];
                acc += pool[P_VWT + d * 32 + c] * mv;
            }
        }
        pool[P_A12 + c * 128 + col] = acc;
    }
    if (tid < 128) {
        int col = tid;
        float acc = 0.f;
        if (col < 32) {
            for (int d = 0; d < 32; ++d)
                acc += to_slot_b[d] * pool[P_KQ + d * 32 + col];
        } else {
            int e = col - 32;
            for (int d = 0; d < 32; ++d) {
                int i = d * 96 + e;
                float mv = (i < 2432) ? pool[P_WHH + 1024 + i] : pool[P_FEAT + i - 2432];
                acc += to_slot_b[d] * mv;
            }
        }
        pool[P_C12 + col] = acc;
    }
    __syncthreads();

    // ---- S3: register-resident time-invariant weights; slots; X(0) ----
    const int o_c = tid & 31;
    float4 cw4[8];
    {
        const float4* wp = (const float4*)(conv_w + o_c * 32);
#pragma unroll
        for (int c = 0; c < 8; ++c) cw4[c] = wp[c];
    }
    const float cb = conv_b[o_c];

    const int idxA = tid - 64;
    const int shhA = (idxA >= 0) ? idxA / 96 : 0;
    const int e3 = (idxA >= 0) ? idxA - shhA * 96 : 0;
    const int s0A = shhA * 2;
    float4 wh4[8];
    float bh = 0.f;
    if (wid > 0) {
        const float4* wp = (const float4*)(whh + e3 * 32);
#pragma unroll
        for (int c = 0; c < 8; ++c) wh4[c] = wp[c];
        bh = bhh[e3];
    }
    const int dB = tid & 31;
    const int sB = tid >> 5;
    float bi0 = 0.f, bi1 = 0.f, bi2 = 0.f;
    if (tid < 128) {
        bi0 = bih[dB]; bi1 = bih[32 + dB]; bi2 = bih[64 + dB];
        pool[P_SLOTS + sB * 36 + dB] = slot_mu[tid];
    }

    const float* fb = frames + (size_t)b * (128 * 256);
    if (tid < 128) {
        int h = tid >> 6, ll = tid & 63;
        int i = ll >> 2, j4 = ll & 3;
        float4 v = *(const float4*)&fb[(h ? 0 : 256) + i * 16 + j4 * 4];
        int n = (i >> 2) * 4 + j4, p = i & 3;
        *(float4*)&pool[P_X + n * 36 + h * 16 + p * 4] = v;
    }
    __syncthreads();

    // ---- Prologue: P1(step 0), all threads ----
    {
        int ng = tid >> 5;
        const float* xa = &pool[P_X + ng * 36];
        const float* xb = &pool[P_X + (ng + 8) * 36];
        float acca = cb, accb = cb;
#pragma unroll
        for (int c = 0; c < 8; ++c) {
            float4 a4 = *(const float4*)&xa[c * 4];
            float4 b4 = *(const float4*)&xb[c * 4];
            acca += cw4[c].x * a4.x + cw4[c].y * a4.y + cw4[c].z * a4.z + cw4[c].w * a4.w;
            accb += cw4[c].x * b4.x + cw4[c].y * b4.y + cw4[c].z * b4.z + cw4[c].w * b4.w;
        }
        pool[P_FEAT + ng * 36 + o_c] = fast_gelu(acca);
        pool[P_FEAT + (ng + 8) * 36 + o_c] = fast_gelu(accb);
    }
    __syncthreads();

    float* so = slots_out + (size_t)b * (126 * 128);

#pragma unroll 1
    for (int t = 0; t < 126; ++t) {
        // ---- P2: KQV GEMM + X(t+1) prefetch ----
        float4 pf;
        const bool havepf = (t < 125) && (tid < 128);
        if (havepf) {
            int h = tid >> 6, ll = tid & 63;
            int i = ll >> 2, j4 = ll & 3;
            pf = *(const float4*)&fb[(t + (h ? 1 : 2)) * 256 + i * 16 + j4 * 4];
        }
        {
            const int cg = tid & 63;
            const int wv = tid >> 6;
            const int col0 = cg * 2;
            float accx[4], accy[4];
#pragma unroll
            for (int j = 0; j < 4; ++j) { accx[j] = 0.f; accy[j] = 0.f; }
#pragma unroll
            for (int c = 0; c < 32; c += 4) {
                float2 a0 = *(const float2*)&pool[P_A12 + (c + 0) * 128 + col0];
                float2 a1 = *(const float2*)&pool[P_A12 + (c + 1) * 128 + col0];
                float2 a2 = *(const float2*)&pool[P_A12 + (c + 2) * 128 + col0];
                float2 a3 = *(const float2*)&pool[P_A12 + (c + 3) * 128 + col0];
#pragma unroll
                for (int j = 0; j < 4; ++j) {
                    float4 q = *(const float4*)&pool[P_FEAT + (wv * 4 + j) * 36 + c];
                    accx[j] += a0.x * q.x + a1.x * q.y + a2.x * q.z + a3.x * q.w;
                    accy[j] += a0.y * q.x + a1.y * q.y + a2.y * q.z + a3.y * q.w;
                }
            }
            float cx = pool[P_C12 + col0], cy = pool[P_C12 + col0 + 1];
            if (col0 < 32) {
#pragma unroll
                for (int j = 0; j < 4; ++j) {
                    int n = wv * 4 + j;
                    *(float2*)&pool[P_KQ + n * 36 + col0] =
                        make_float2(accx[j] + cx, accy[j] + cy);
                }
            } else {
                int e0 = col0 - 32;
                int sw0 = (e0 >> 3) & 3;
                int sw1 = ((e0 + 1) >> 3) & 3;
                float4 w0 = make_float4(accx[0] + cx, accx[1] + cx,
                                        accx[2] + cx, accx[3] + cx);
                float4 w1 = make_float4(accy[0] + cy, accy[1] + cy,
                                        accy[2] + cy, accy[3] + cy);
                *(float4*)&pool[P_VWT + e0 * 20 + ((wv ^ sw0) << 2)] = w0;
                *(float4*)&pool[P_VWT + (e0 + 1) * 20 + ((wv ^ sw1) << 2)] = w1;
            }
        }
        if (havepf) {
            int h = tid >> 6, ll = tid & 63;
            int i = ll >> 2, j4 = ll & 3;
            int n = (i >> 2) * 4 + j4, p = i & 3;
            *(float4*)&pool[P_X + n * 36 + h * 16 + p * 4] = pf;
        }
        __syncthreads();   // BAR (P2 done; X(t+1) visible)

        // ---- 3 attention iterations; conv(t+1) hidden in phase B of it 0,1 ----
#pragma unroll 1
        for (int it = 0; it < 3; ++it) {
            // phase A: wave0 logits + shfl-softmax (setprio); waves1-3 gh
            if (wid == 0) {
                __builtin_amdgcn_s_setprio(1);
                int s = lane >> 4, n = lane & 15;
                const float* sp = &pool[P_SLOTS + s * 36];
                const float* kp = &pool[P_KQ + n * 36];
                float acc = 0.f;
#pragma unroll
                for (int d = 0; d < 32; d += 4) {
                    float4 a = *(const float4*)&sp[d];
                    float4 c = *(const float4*)&kp[d];
                    acc += a.x * c.x + a.y * c.y + a.z * c.z + a.w * c.w;
                }
                float lg = acc * 0.17677669529663687f;  // 1/sqrt(32)
                float m = fmaxf(lg, __shfl_xor(lg, 16));
                m = fmaxf(m, __shfl_xor(m, 32));
                float e = __expf(lg - m);
                float ssum = e + __shfl_xor(e, 16);
                ssum += __shfl_xor(ssum, 32);
                pool[P_ATTN + s * 20 + n] = e / ssum;
                __builtin_amdgcn_s_setprio(0);
            } else {
                const float* sa = &pool[P_SLOTS + s0A * 36];
                const float* sb = &pool[P_SLOTS + (s0A + 1) * 36];
                float acc0 = bh, acc1 = bh;
#pragma unroll
                for (int c = 0; c < 8; ++c) {
                    float4 a4 = *(const float4*)&sa[c * 4];
                    float4 b4 = *(const float4*)&sb[c * 4];
                    acc0 += wh4[c].x * a4.x + wh4[c].y * a4.y + wh4[c].z * a4.z + wh4[c].w * a4.w;
                    acc1 += wh4[c].x * b4.x + wh4[c].y * b4.y + wh4[c].z * b4.z + wh4[c].w * b4.w;
                }
                pool[P_GH + s0A * 100 + e3] = acc0;
                pool[P_GH + (s0A + 1) * 100 + e3] = acc1;
            }
            __syncthreads();   // BAR A->B

            // phase B: tid<128 gi+combine (setprio'd critical chain);
            //          tid>=128 conv(t+1) rows 8*it..8*it+7 (it<2)
            if (tid < 128) {
                __builtin_amdgcn_s_setprio(1);
                float ar[16];
#pragma unroll
                for (int k = 0; k < 16; k += 4) {
                    float4 a4 = *(const float4*)&pool[P_ATTN + sB * 20 + k];
                    ar[k] = a4.x; ar[k + 1] = a4.y; ar[k + 2] = a4.z; ar[k + 3] = a4.w;
                }
                const int sw = (dB >> 3) & 3;
                const float* v0 = &pool[P_VWT + dB * 20];
                const float* v1 = &pool[P_VWT + (dB + 32) * 20];
                const float* v2 = &pool[P_VWT + (dB + 64) * 20];
                float gir = bi0, giz = bi1, gin = bi2;
#pragma unroll
                for (int n4 = 0; n4 < 4; ++n4) {
                    int ph = (n4 ^ sw) << 2;
                    float4 x0 = *(const float4*)&v0[ph];
                    float4 x1 = *(const float4*)&v1[ph];
                    float4 x2 = *(const float4*)&v2[ph];
                    int n = n4 * 4;
                    gir += ar[n] * x0.x + ar[n + 1] * x0.y + ar[n + 2] * x0.z + ar[n + 3] * x0.w;
                    giz += ar[n] * x1.x + ar[n + 1] * x1.y + ar[n + 2] * x1.z + ar[n + 3] * x1.w;
                    gin += ar[n] * x2.x + ar[n + 1] * x2.y + ar[n + 2] * x2.z + ar[n + 3] * x2.w;
                }
                float ghr = pool[P_GH + sB * 100 + dB];
                float ghz = pool[P_GH + sB * 100 + 32 + dB];
                float ghn = pool[P_GH + sB * 100 + 64 + dB];
                float r = fast_sigmoid(gir + ghr);
                float z = fast_sigmoid(giz + ghz);
                float nn = fast_tanh(gin + r * ghn);
                float h = pool[P_SLOTS + sB * 36 + dB];
                float hn = (1.0f - z) * nn + z * h;
                pool[P_SLOTS + sB * 36 + dB] = hn;
                if (it == 2) so[t * 128 + tid] = hn;
                __builtin_amdgcn_s_setprio(0);
            } else if (it < 2 && t < 125) {
                int tid2 = tid - 128;
                int rbase = it * 8 + (tid2 >> 5) * 2;
#pragma unroll
                for (int j = 0; j < 2; ++j) {
                    int n = rbase + j;
                    const float* xr = &pool[P_X + n * 36];
                    float acc = cb;
#pragma unroll
                    for (int c = 0; c < 8; ++c) {
                        float4 x4 = *(const float4*)&xr[c * 4];
                        acc += cw4[c].x * x4.x + cw4[c].y * x4.y
                             + cw4[c].z * x4.z + cw4[c].w * x4.w;
                    }
                    pool[P_FEAT + n * 36 + o_c] = fast_gelu(acc);
                }
            }
            __syncthreads();   // BAR B->next
        }
    }
}

// ---------------------------------------------------------------------------
// Kernel B (decode_mfma): byte-identical to round-15/16 verified version.
// ---------------------------------------------------------------------------
__global__ __launch_bounds__(TB, 1) void decode_mfma(
    const float* __restrict__ slots_traj, const float* __restrict__ frames,
    const float* __restrict__ dec_w, const float* __restrict__ dec_b,
    const float* __restrict__ deconv_w, const float* __restrict__ deconv_b,
    float* __restrict__ out)
{
    const int tid = threadIdx.x;
    const int l = tid & 63;
    const int w = tid >> 6;
    const int m0 = blockIdx.x * 64;

    __shared__ short A_lds[64 * 136];
    __shared__ short B_lds[64 * 136];
    __shared__ float dw_s[512];
    __shared__ float dbd_s[256];

    {
        int row = tid >> 2, kq = (tid & 3) * 32;
        const float* src = slots_traj + (size_t)(m0 + row) * 128 + kq;
        short tmp[32];
#pragma unroll
        for (int i = 0; i < 32; i += 4) {
            float4 v = *(const float4*)&src[i];
            tmp[i] = f2bf(v.x); tmp[i + 1] = f2bf(v.y);
            tmp[i + 2] = f2bf(v.z); tmp[i + 3] = f2bf(v.w);
        }
        short* dst = &A_lds[row * 136 + kq];
#pragma unroll
        for (int i = 0; i < 4; ++i)
            *(bf16x8*)&dst[i * 8] = *(bf16x8*)&tmp[i * 8];
    }
    for (int i = tid; i < 512; i += TB) dw_s[i] = deconv_w[i];
    {
        int sp = tid >> 4, kl = tid & 15;
        float acc = 0.f;
#pragma unroll 8
        for (int c = 0; c < 32; ++c)
            acc += dec_b[16 * c + sp] * deconv_w[c * 16 + kl];
        dbd_s[tid] = acc;
    }
    __syncthreads();

    bf16x8 afr[4];
#pragma unroll
    for (int ks = 0; ks < 4; ++ks)
        afr[ks] = *(const bf16x8*)&A_lds[(16 * w + (l & 15)) * 136 + ks * 32 + (l >> 4) * 8];

    float part[4][16];
#pragma unroll
    for (int r = 0; r < 4; ++r)
#pragma unroll
        for (int kl = 0; kl < 16; ++kl) part[r][kl] = 0.f;

#pragma unroll 1
    for (int ch = 0; ch < 8; ++ch) {
        {
            int row = tid >> 2, kq = (tid & 3) * 32;
            const float* src = dec_w + (size_t)(ch * 64 + row) * 128 + kq;
            short tmp[32];
#pragma unroll
            for (int i = 0; i < 32; i += 4) {
                float4 v = *(const float4*)&src[i];
                tmp[i] = f2bf(v.x); tmp[i + 1] = f2bf(v.y);
                tmp[i + 2] = f2bf(v.z); tmp[i + 3] = f2bf(v.w);
            }
            short* dst = &B_lds[row * 136 + kq];
#pragma unroll
            for (int i = 0; i < 4; ++i)
                *(bf16x8*)&dst[i * 8] = *(bf16x8*)&tmp[i * 8];
        }
        __syncthreads();

#pragma unroll
        for (int ct = 0; ct < 4; ++ct) {
            f32x4 acc = {0.f, 0.f, 0.f, 0.f};
#pragma unroll
            for (int ks = 0; ks < 4; ++ks) {
                bf16x8 bfr = *(const bf16x8*)&B_lds[(ct * 16 + (l & 15)) * 136 + ks * 32 + (l >> 4) * 8];
                acc = __builtin_amdgcn_mfma_f32_16x16x32_bf16(afr[ks], bfr, acc, 0, 0, 0);
            }
            const float* dwp = &dw_s[(4 * ch + ct) * 16];
#pragma unroll
            for (int r = 0; r < 4; ++r) {
                float v = acc[r];
#pragma unroll
                for (int kl = 0; kl < 16; ++kl) part[r][kl] += v * dwp[kl];
            }
        }
        __syncthreads();
    }

    const int sp = l & 15;
    const int bi = sp >> 2, bj = sp & 3;
    const float db0 = deconv_b[0];
    float dbdv[16];
#pragma unroll
    for (int kl = 0; kl < 16; ++kl) dbdv[kl] = dbd_s[sp * 16 + kl];

#pragma unroll
    for (int r = 0; r < 4; ++r) {
        int mrow = m0 + 16 * w + (l >> 4) * 4 + r;
        int bb = mrow / 126, tt = mrow - bb * 126;
        const float* fr = frames + ((size_t)bb * 128 + (tt + 1)) * 256;
        float* op = out + (size_t)mrow * 256;
#pragma unroll
        for (int kk = 0; kk < 4; ++kk) {
            int pixb = (bi * 4 + kk) * 16 + bj * 4;
            float4 c4 = *(const float4*)&fr[pixb];
            float4 o4;
            o4.x = fminf(fmaxf(c4.x + tanhf(part[r][kk * 4 + 0] + dbdv[kk * 4 + 0] + db0), 0.f), 1.f);
            o4.y = fminf(fmaxf(c4.y + tanhf(part[r][kk * 4 + 1] + dbdv[kk * 4 + 1] + db0), 0.f), 1.f);
            o4.z = fminf(fmaxf(c4.z + tanhf(part[r][kk * 4 + 2] + dbdv[kk * 4 + 2] + db0), 0.f), 1.f);
            o4.w = fminf(fmaxf(c4.w + tanhf(part[r][kk * 4 + 3] + dbdv[kk * 4 + 3] + db0), 0.f), 1.f);
            *(float4*)&op[pixb] = o4;
        }
    }
}

extern "C" void kernel_launch(void* const* d_in, const int* in_sizes, int n_in,
                              void* d_out, int out_size, void* d_ws, size_t ws_size,
                              hipStream_t stream) {
    const float* frames    = (const float*)d_in[0];
    const float* slot_mu   = (const float*)d_in[1];
    const float* conv_w    = (const float*)d_in[2];
    const float* conv_b    = (const float*)d_in[3];
    const float* to_slot_w = (const float*)d_in[4];
    const float* to_slot_b = (const float*)d_in[5];
    const float* q_w       = (const float*)d_in[6];
    const float* k_w       = (const float*)d_in[7];
    const float* v_w       = (const float*)d_in[8];
    const float* gru_wih   = (const float*)d_in[9];
    const float* gru_whh   = (const float*)d_in[10];
    const float* gru_bih   = (const float*)d_in[11];
    const float* gru_bhh   = (const float*)d_in[12];
    const float* dec_w     = (const float*)d_in[13];
    const float* dec_b     = (const float*)d_in[14];
    const float* deconv_w  = (const float*)d_in[15];
    const float* deconv_b  = (const float*)d_in[16];

    float* slots_traj = (float*)d_ws;  // 512*126*128 floats = 33 MB
    float* outp = (float*)d_out;

    hipLaunchKernelGGL(slot_recur_kernel, dim3(512), dim3(256), 0, stream,
                       frames, slot_mu, conv_w, conv_b, to_slot_w, to_slot_b,
                       q_w, k_w, v_w, gru_wih, gru_whh, gru_bih, gru_bhh,
                       slots_traj);
    hipLaunchKernelGGL(decode_mfma, dim3(64512 / 64), dim3(TB), 0, stream,
                       slots_traj, frames, dec_w, dec_b, deconv_w, deconv_b,
                       outp);
}

// Round 19
// 670.750 us; speedup vs baseline: 1.3105x; 1.0261x over previous
//
#include <hip/hip_runtime.h>
#include <math.h>

#define TB 256

typedef __attribute__((ext_vector_type(8))) short bf16x8;
typedef __attribute__((ext_vector_type(4))) float f32x4;

__device__ __forceinline__ float fast_sigmoid(float x) {
    return 1.0f / (1.0f + __expf(-x));
}
__device__ __forceinline__ float fast_tanh(float x) {
    float a = fabsf(x);
    float e = __expf(2.0f * a);
    float r = 1.0f - 2.0f / (e + 1.0f);
    return copysignf(r, x);
}
// tanh-form GELU: max |err| vs exact ~3e-4, far below the 2e-2 threshold
__device__ __forceinline__ float fast_gelu(float x) {
    float x3 = x * x * x;
    return 0.5f * x * (1.0f + fast_tanh(0.7978845608028654f * (x + 0.044715f * x3)));
}
// fp32 -> bf16 (RNE)
__device__ __forceinline__ short f2bf(float f) {
    unsigned u = __float_as_uint(f);
    unsigned r = (u + 0x7FFFu + ((u >> 16) & 1u)) >> 16;
    return (short)r;
}

// ---------------------------------------------------------------------------
// LDS pool (floats), 48.6 KB (round-14/16/18 layout, verified).
// ---------------------------------------------------------------------------
#define P_A12   0        // 4096 : A12 [c][col] stride 128 (setup + reg-cache src)
#define P_C12   4096     // 128
#define P_WHH   4224     // 3456 : setup scratch (staged v/k/q, MvW split)
#define P_VWT   7680     // 1920 : vWT [e][n-swizzled] stride 20
#define P_KQ    9600     // 576  : kq  [n][d] stride 36
#define P_X     10176    // 576  : X   [n][k] stride 36
#define P_FEAT  10752    // 576  : feat[n][c] stride 36
#define P_SLOTS 11328    // 144  : slots [s][d] stride 36
#define P_ATTN  11472    // 80   : attn [s][n] stride 20
#define P_GH    11552    // 400  : gh [s][e] stride 100
#define P_SZ    12144

// ---------------------------------------------------------------------------
// Kernel A: round-18 verified structure (700 us) + A12/c12 columns cached in
// REGISTERS (time-invariant per-thread: ax[32], ay[32], cx, cy; static
// indices only). Deletes the P2 phase's 32x b64 A12 LDS stream (the longest
// phase's dominant traffic + main surviving conflict source).
// Per step: P2 KQV + X(t+1) prefetch | 3x { [wave0 logits+softmax (setprio) ||
// waves1-3 gh (reg whh)] | [tid<128 gi+combine (setprio) || tid>=128
// conv(t+1) halves] }. 7 barriers/step.
// Fused weights (verified rounds 2-18):
//   Mkq[d][dp] = sum_e k_w[e][d] q_w[e][dp]
//   MvW[d][e]  = sum_e' v_w[e'][d] wih[e][e']
//   A12[c][col] = sum_d wts[d][c] * (col<32 ? Mkq[d][col] : MvW[d][col-32])
//   c12[col]    = sum_d bts[d]   * (same)
// ---------------------------------------------------------------------------
__global__ __launch_bounds__(256, 2) void slot_recur_kernel(
    const float* __restrict__ frames, const float* __restrict__ slot_mu,
    const float* __restrict__ conv_w, const float* __restrict__ conv_b,
    const float* __restrict__ to_slot_w, const float* __restrict__ to_slot_b,
    const float* __restrict__ q_w, const float* __restrict__ k_w,
    const float* __restrict__ v_w,
    const float* __restrict__ wih, const float* __restrict__ whh,
    const float* __restrict__ bih, const float* __restrict__ bhh,
    float* __restrict__ slots_out)
{
    const int tid = threadIdx.x;
    const int b = blockIdx.x;
    const int lane = tid & 63;
    const int wid = tid >> 6;

    __shared__ float pool[P_SZ];

    // ---- S0: stage raw weights into aliased regions ----
    for (int i = tid; i < 3072; i += 256) pool[P_A12 + i] = wih[i];
    for (int i = tid; i < 1024; i += 256) {
        pool[P_WHH + i]        = v_w[i];
        pool[P_WHH + 1024 + i] = k_w[i];
        pool[P_WHH + 2048 + i] = q_w[i];
        pool[P_VWT + i]        = to_slot_w[i];
    }
    __syncthreads();

    // ---- S1a: Mkq ----
    for (int o = tid; o < 1024; o += 256) {
        int d = o >> 5, dp = o & 31;
        float acc = 0.f;
#pragma unroll 8
        for (int e = 0; e < 32; ++e)
            acc += pool[P_WHH + 1024 + e * 32 + d] * pool[P_WHH + 2048 + e * 32 + dp];
        pool[P_KQ + o] = acc;
    }
    __syncthreads();

    // ---- S1b: MvW (split store) ----
    for (int o = tid; o < 3072; o += 256) {
        int d = o / 96, e = o - d * 96;
        float acc = 0.f;
#pragma unroll 8
        for (int ep = 0; ep < 32; ++ep)
            acc += pool[P_WHH + ep * 32 + d] * pool[P_A12 + e * 32 + ep];
        if (o < 2432) pool[P_WHH + 1024 + o] = acc;
        else          pool[P_FEAT + o - 2432] = acc;
    }
    __syncthreads();

    // ---- S2: A12/c12 ----
    for (int o = tid; o < 4096; o += 256) {
        int c = o >> 7, col = o & 127;
        float acc = 0.f;
        if (col < 32) {
#pragma unroll 8
            for (int d = 0; d < 32; ++d)
                acc += pool[P_VWT + d * 32 + c] * pool[P_KQ + d * 32 + col];
        } else {
            int e = col - 32;
#pragma unroll 8
            for (int d = 0; d < 32; ++d) {
                int i = d * 96 + e;
                float mv = (i < 2432) ? pool[P_WHH + 1024 + i] : pool[P_FEAT + i - 2432];
                acc += pool[P_VWT + d * 32 + c] * mv;
            }
        }
        pool[P_A12 + c * 128 + col] = acc;
    }
    if (tid < 128) {
        int col = tid;
        float acc = 0.f;
        if (col < 32) {
            for (int d = 0; d < 32; ++d)
                acc += to_slot_b[d] * pool[P_KQ + d * 32 + col];
        } else {
            int e = col - 32;
            for (int d = 0; d < 32; ++d) {
                int i = d * 96 + e;
                float mv = (i < 2432) ? pool[P_WHH + 1024 + i] : pool[P_FEAT + i - 2432];
                acc += to_slot_b[d] * mv;
            }
        }
        pool[P_C12 + col] = acc;
    }
    __syncthreads();

    // ---- S3: register caches (A12 cols, conv row, whh row), slots, X(0) ----
    const int cg_p = tid & 63;
    const int col0 = cg_p * 2;
    float ax[32], ay[32];
#pragma unroll
    for (int c = 0; c < 32; ++c) {
        float2 t = *(const float2*)&pool[P_A12 + c * 128 + col0];
        ax[c] = t.x; ay[c] = t.y;
    }
    const float cx = pool[P_C12 + col0];
    const float cy = pool[P_C12 + col0 + 1];

    const int o_c = tid & 31;
    float4 cw4[8];
    {
        const float4* wp = (const float4*)(conv_w + o_c * 32);
#pragma unroll
        for (int c = 0; c < 8; ++c) cw4[c] = wp[c];
    }
    const float cb = conv_b[o_c];

    const int idxA = tid - 64;
    const int shhA = (idxA >= 0) ? idxA / 96 : 0;
    const int e3 = (idxA >= 0) ? idxA - shhA * 96 : 0;
    const int s0A = shhA * 2;
    float4 wh4[8];
    float bh = 0.f;
    if (wid > 0) {
        const float4* wp = (const float4*)(whh + e3 * 32);
#pragma unroll
        for (int c = 0; c < 8; ++c) wh4[c] = wp[c];
        bh = bhh[e3];
    }
    const int dB = tid & 31;
    const int sB = tid >> 5;
    float bi0 = 0.f, bi1 = 0.f, bi2 = 0.f;
    if (tid < 128) {
        bi0 = bih[dB]; bi1 = bih[32 + dB]; bi2 = bih[64 + dB];
        pool[P_SLOTS + sB * 36 + dB] = slot_mu[tid];
    }

    const float* fb = frames + (size_t)b * (128 * 256);
    if (tid < 128) {
        int h = tid >> 6, ll = tid & 63;
        int i = ll >> 2, j4 = ll & 3;
        float4 v = *(const float4*)&fb[(h ? 0 : 256) + i * 16 + j4 * 4];
        int n = (i >> 2) * 4 + j4, p = i & 3;
        *(float4*)&pool[P_X + n * 36 + h * 16 + p * 4] = v;
    }
    __syncthreads();

    // ---- Prologue: P1(step 0), all threads ----
    {
        int ng = tid >> 5;
        const float* xa = &pool[P_X + ng * 36];
        const float* xb = &pool[P_X + (ng + 8) * 36];
        float acca = cb, accb = cb;
#pragma unroll
        for (int c = 0; c < 8; ++c) {
            float4 a4 = *(const float4*)&xa[c * 4];
            float4 b4 = *(const float4*)&xb[c * 4];
            acca += cw4[c].x * a4.x + cw4[c].y * a4.y + cw4[c].z * a4.z + cw4[c].w * a4.w;
            accb += cw4[c].x * b4.x + cw4[c].y * b4.y + cw4[c].z * b4.z + cw4[c].w * b4.w;
        }
        pool[P_FEAT + ng * 36 + o_c] = fast_gelu(acca);
        pool[P_FEAT + (ng + 8) * 36 + o_c] = fast_gelu(accb);
    }
    __syncthreads();

    float* so = slots_out + (size_t)b * (126 * 128);

#pragma unroll 1
    for (int t = 0; t < 126; ++t) {
        // ---- P2: KQV GEMM (A12 from regs) + X(t+1) prefetch ----
        float4 pf;
        const bool havepf = (t < 125) && (tid < 128);
        if (havepf) {
            int h = tid >> 6, ll = tid & 63;
            int i = ll >> 2, j4 = ll & 3;
            pf = *(const float4*)&fb[(t + (h ? 1 : 2)) * 256 + i * 16 + j4 * 4];
        }
        {
            const int wv = tid >> 6;
            float accx[4], accy[4];
#pragma unroll
            for (int j = 0; j < 4; ++j) { accx[j] = 0.f; accy[j] = 0.f; }
#pragma unroll
            for (int c = 0; c < 32; c += 4) {
#pragma unroll
                for (int j = 0; j < 4; ++j) {
                    float4 q = *(const float4*)&pool[P_FEAT + (wv * 4 + j) * 36 + c];
                    accx[j] += ax[c] * q.x + ax[c + 1] * q.y + ax[c + 2] * q.z + ax[c + 3] * q.w;
                    accy[j] += ay[c] * q.x + ay[c + 1] * q.y + ay[c + 2] * q.z + ay[c + 3] * q.w;
                }
            }
            if (col0 < 32) {
#pragma unroll
                for (int j = 0; j < 4; ++j) {
                    int n = wv * 4 + j;
                    *(float2*)&pool[P_KQ + n * 36 + col0] =
                        make_float2(accx[j] + cx, accy[j] + cy);
                }
            } else {
                int e0 = col0 - 32;
                int sw0 = (e0 >> 3) & 3;
                int sw1 = ((e0 + 1) >> 3) & 3;
                float4 w0 = make_float4(accx[0] + cx, accx[1] + cx,
                                        accx[2] + cx, accx[3] + cx);
                float4 w1 = make_float4(accy[0] + cy, accy[1] + cy,
                                        accy[2] + cy, accy[3] + cy);
                *(float4*)&pool[P_VWT + e0 * 20 + ((wv ^ sw0) << 2)] = w0;
                *(float4*)&pool[P_VWT + (e0 + 1) * 20 + ((wv ^ sw1) << 2)] = w1;
            }
        }
        if (havepf) {
            int h = tid >> 6, ll = tid & 63;
            int i = ll >> 2, j4 = ll & 3;
            int n = (i >> 2) * 4 + j4, p = i & 3;
            *(float4*)&pool[P_X + n * 36 + h * 16 + p * 4] = pf;
        }
        __syncthreads();   // BAR (P2 done; X(t+1) visible)

        // ---- 3 attention iterations; conv(t+1) hidden in phase B of it 0,1 ----
#pragma unroll 1
        for (int it = 0; it < 3; ++it) {
            // phase A: wave0 logits + shfl-softmax (setprio); waves1-3 gh
            if (wid == 0) {
                __builtin_amdgcn_s_setprio(1);
                int s = lane >> 4, n = lane & 15;
                const float* sp = &pool[P_SLOTS + s * 36];
                const float* kp = &pool[P_KQ + n * 36];
                float acc = 0.f;
#pragma unroll
                for (int d = 0; d < 32; d += 4) {
                    float4 a = *(const float4*)&sp[d];
                    float4 c = *(const float4*)&kp[d];
                    acc += a.x * c.x + a.y * c.y + a.z * c.z + a.w * c.w;
                }
                float lg = acc * 0.17677669529663687f;  // 1/sqrt(32)
                float m = fmaxf(lg, __shfl_xor(lg, 16));
                m = fmaxf(m, __shfl_xor(m, 32));
                float e = __expf(lg - m);
                float ssum = e + __shfl_xor(e, 16);
                ssum += __shfl_xor(ssum, 32);
                pool[P_ATTN + s * 20 + n] = e / ssum;
                __builtin_amdgcn_s_setprio(0);
            } else {
                const float* sa = &pool[P_SLOTS + s0A * 36];
                const float* sb = &pool[P_SLOTS + (s0A + 1) * 36];
                float acc0 = bh, acc1 = bh;
#pragma unroll
                for (int c = 0; c < 8; ++c) {
                    float4 a4 = *(const float4*)&sa[c * 4];
                    float4 b4 = *(const float4*)&sb[c * 4];
                    acc0 += wh4[c].x * a4.x + wh4[c].y * a4.y + wh4[c].z * a4.z + wh4[c].w * a4.w;
                    acc1 += wh4[c].x * b4.x + wh4[c].y * b4.y + wh4[c].z * b4.z + wh4[c].w * b4.w;
                }
                pool[P_GH + s0A * 100 + e3] = acc0;
                pool[P_GH + (s0A + 1) * 100 + e3] = acc1;
            }
            __syncthreads();   // BAR A->B

            // phase B: tid<128 gi+combine (setprio); tid>=128 conv(t+1) halves
            if (tid < 128) {
                __builtin_amdgcn_s_setprio(1);
                float ar[16];
#pragma unroll
                for (int k = 0; k < 16; k += 4) {
                    float4 a4 = *(const float4*)&pool[P_ATTN + sB * 20 + k];
                    ar[k] = a4.x; ar[k + 1] = a4.y; ar[k + 2] = a4.z; ar[k + 3] = a4.w;
                }
                const int sw = (dB >> 3) & 3;
                const float* v0 = &pool[P_VWT + dB * 20];
                const float* v1 = &pool[P_VWT + (dB + 32) * 20];
                const float* v2 = &pool[P_VWT + (dB + 64) * 20];
                float gir = bi0, giz = bi1, gin = bi2;
#pragma unroll
                for (int n4 = 0; n4 < 4; ++n4) {
                    int ph = (n4 ^ sw) << 2;
                    float4 x0 = *(const float4*)&v0[ph];
                    float4 x1 = *(const float4*)&v1[ph];
                    float4 x2 = *(const float4*)&v2[ph];
                    int n = n4 * 4;
                    gir += ar[n] * x0.x + ar[n + 1] * x0.y + ar[n + 2] * x0.z + ar[n + 3] * x0.w;
                    giz += ar[n] * x1.x + ar[n + 1] * x1.y + ar[n + 2] * x1.z + ar[n + 3] * x1.w;
                    gin += ar[n] * x2.x + ar[n + 1] * x2.y + ar[n + 2] * x2.z + ar[n + 3] * x2.w;
                }
                float ghr = pool[P_GH + sB * 100 + dB];
                float ghz = pool[P_GH + sB * 100 + 32 + dB];
                float ghn = pool[P_GH + sB * 100 + 64 + dB];
                float r = fast_sigmoid(gir + ghr);
                float z = fast_sigmoid(giz + ghz);
                float nn = fast_tanh(gin + r * ghn);
                float h = pool[P_SLOTS + sB * 36 + dB];
                float hn = (1.0f - z) * nn + z * h;
                pool[P_SLOTS + sB * 36 + dB] = hn;
                if (it == 2) so[t * 128 + tid] = hn;
                __builtin_amdgcn_s_setprio(0);
            } else if (it < 2 && t < 125) {
                int tid2 = tid - 128;
                int rbase = it * 8 + (tid2 >> 5) * 2;
#pragma unroll
                for (int j = 0; j < 2; ++j) {
                    int n = rbase + j;
                    const float* xr = &pool[P_X + n * 36];
                    float acc = cb;
#pragma unroll
                    for (int c = 0; c < 8; ++c) {
                        float4 x4 = *(const float4*)&xr[c * 4];
                        acc += cw4[c].x * x4.x + cw4[c].y * x4.y
                             + cw4[c].z * x4.z + cw4[c].w * x4.w;
                    }
                    pool[P_FEAT + n * 36 + o_c] = fast_gelu(acc);
                }
            }
            __syncthreads();   // BAR B->next
        }
    }
}

// ---------------------------------------------------------------------------
// Kernel B (decode_mfma): byte-identical to round-15/16/18 verified version.
// ---------------------------------------------------------------------------
__global__ __launch_bounds__(TB, 1) void decode_mfma(
    const float* __restrict__ slots_traj, const float* __restrict__ frames,
    const float* __restrict__ dec_w, const float* __restrict__ dec_b,
    const float* __restrict__ deconv_w, const float* __restrict__ deconv_b,
    float* __restrict__ out)
{
    const int tid = threadIdx.x;
    const int l = tid & 63;
    const int w = tid >> 6;
    const int m0 = blockIdx.x * 64;

    __shared__ short A_lds[64 * 136];
    __shared__ short B_lds[64 * 136];
    __shared__ float dw_s[512];
    __shared__ float dbd_s[256];

    {
        int row = tid >> 2, kq = (tid & 3) * 32;
        const float* src = slots_traj + (size_t)(m0 + row) * 128 + kq;
        short tmp[32];
#pragma unroll
        for (int i = 0; i < 32; i += 4) {
            float4 v = *(const float4*)&src[i];
            tmp[i] = f2bf(v.x); tmp[i + 1] = f2bf(v.y);
            tmp[i + 2] = f2bf(v.z); tmp[i + 3] = f2bf(v.w);
        }
        short* dst = &A_lds[row * 136 + kq];
#pragma unroll
        for (int i = 0; i < 4; ++i)
            *(bf16x8*)&dst[i * 8] = *(bf16x8*)&tmp[i * 8];
    }
    for (int i = tid; i < 512; i += TB) dw_s[i] = deconv_w[i];
    {
        int sp = tid >> 4, kl = tid & 15;
        float acc = 0.f;
#pragma unroll 8
        for (int c = 0; c < 32; ++c)
            acc += dec_b[16 * c + sp] * deconv_w[c * 16 + kl];
        dbd_s[tid] = acc;
    }
    __syncthreads();

    bf16x8 afr[4];
#pragma unroll
    for (int ks = 0; ks < 4; ++ks)
        afr[ks] = *(const bf16x8*)&A_lds[(16 * w + (l & 15)) * 136 + ks * 32 + (l >> 4) * 8];

    float part[4][16];
#pragma unroll
    for (int r = 0; r < 4; ++r)
#pragma unroll
        for (int kl = 0; kl < 16; ++kl) part[r][kl] = 0.f;

#pragma unroll 1
    for (int ch = 0; ch < 8; ++ch) {
        {
            int row = tid >> 2, kq = (tid & 3) * 32;
            const float* src = dec_w + (size_t)(ch * 64 + row) * 128 + kq;
            short tmp[32];
#pragma unroll
            for (int i = 0; i < 32; i += 4) {
                float4 v = *(const float4*)&src[i];
                tmp[i] = f2bf(v.x); tmp[i + 1] = f2bf(v.y);
                tmp[i + 2] = f2bf(v.z); tmp[i + 3] = f2bf(v.w);
            }
            short* dst = &B_lds[row * 136 + kq];
#pragma unroll
            for (int i = 0; i < 4; ++i)
                *(bf16x8*)&dst[i * 8] = *(bf16x8*)&tmp[i * 8];
        }
        __syncthreads();

#pragma unroll
        for (int ct = 0; ct < 4; ++ct) {
            f32x4 acc = {0.f, 0.f, 0.f, 0.f};
#pragma unroll
            for (int ks = 0; ks < 4; ++ks) {
                bf16x8 bfr = *(const bf16x8*)&B_lds[(ct * 16 + (l & 15)) * 136 + ks * 32 + (l >> 4) * 8];
                acc = __builtin_amdgcn_mfma_f32_16x16x32_bf16(afr[ks], bfr, acc, 0, 0, 0);
            }
            const float* dwp = &dw_s[(4 * ch + ct) * 16];
#pragma unroll
            for (int r = 0; r < 4; ++r) {
                float v = acc[r];
#pragma unroll
                for (int kl = 0; kl < 16; ++kl) part[r][kl] += v * dwp[kl];
            }
        }
        __syncthreads();
    }

    const int sp = l & 15;
    const int bi = sp >> 2, bj = sp & 3;
    const float db0 = deconv_b[0];
    float dbdv[16];
#pragma unroll
    for (int kl = 0; kl < 16; ++kl) dbdv[kl] = dbd_s[sp * 16 + kl];

#pragma unroll
    for (int r = 0; r < 4; ++r) {
        int mrow = m0 + 16 * w + (l >> 4) * 4 + r;
        int bb = mrow / 126, tt = mrow - bb * 126;
        const float* fr = frames + ((size_t)bb * 128 + (tt + 1)) * 256;
        float* op = out + (size_t)mrow * 256;
#pragma unroll
        for (int kk = 0; kk < 4; ++kk) {
            int pixb = (bi * 4 + kk) * 16 + bj * 4;
            float4 c4 = *(const float4*)&fr[pixb];
            float4 o4;
            o4.x = fminf(fmaxf(c4.x + tanhf(part[r][kk * 4 + 0] + dbdv[kk * 4 + 0] + db0), 0.f), 1.f);
            o4.y = fminf(fmaxf(c4.y + tanhf(part[r][kk * 4 + 1] + dbdv[kk * 4 + 1] + db0), 0.f), 1.f);
            o4.z = fminf(fmaxf(c4.z + tanhf(part[r][kk * 4 + 2] + dbdv[kk * 4 + 2] + db0), 0.f), 1.f);
            o4.w = fminf(fmaxf(c4.w + tanhf(part[r][kk * 4 + 3] + dbdv[kk * 4 + 3] + db0), 0.f), 1.f);
            *(float4*)&op[pixb] = o4;
        }
    }
}

extern "C" void kernel_launch(void* const* d_in, const int* in_sizes, int n_in,
                              void* d_out, int out_size, void* d_ws, size_t ws_size,
                              hipStream_t stream) {
    const float* frames    = (const float*)d_in[0];
    const float* slot_mu   = (const float*)d_in[1];
    const float* conv_w    = (const float*)d_in[2];
    const float* conv_b    = (const float*)d_in[3];
    const float* to_slot_w = (const float*)d_in[4];
    const float* to_slot_b = (const float*)d_in[5];
    const float* q_w       = (const float*)d_in[6];
    const float* k_w       = (const float*)d_in[7];
    const float* v_w       = (const float*)d_in[8];
    const float* gru_wih   = (const float*)d_in[9];
    const float* gru_whh   = (const float*)d_in[10];
    const float* gru_bih   = (const float*)d_in[11];
    const float* gru_bhh   = (const float*)d_in[12];
    const float* dec_w     = (const float*)d_in[13];
    const float* dec_b     = (const float*)d_in[14];
    const float* deconv_w  = (const float*)d_in[15];
    const float* deconv_b  = (const float*)d_in[16];

    float* slots_traj = (float*)d_ws;  // 512*126*128 floats = 33 MB
    float* outp = (float*)d_out;

    hipLaunchKernelGGL(slot_recur_kernel, dim3(512), dim3(256), 0, stream,
                       frames, slot_mu, conv_w, conv_b, to_slot_w, to_slot_b,
                       q_w, k_w, v_w, gru_wih, gru_whh, gru_bih, gru_bhh,
                       slots_traj);
    hipLaunchKernelGGL(decode_mfma, dim3(64512 / 64), dim3(TB), 0, stream,
                       slots_traj, frames, dec_w, dec_b, deconv_w, deconv_b,
                       outp);
}